// Round 6
// baseline (22.532 us; speedup 1.0000x reference)
//
#include <hip/hip_runtime.h>

#define N_CLASSES 512
#define EPS_F 1e-7f
#define BLOCK 1024
#define RB 16  // partial rows per reduce block

// ---------------- Path A (atomic-free main, 2 nodes, no memset) ------------

// K1: gather + NLL + per-block LDS class histogram; flush = coalesced plain
// stores of per-block partials (every slot written -> no zero-init needed).
// Block 0 also re-zeros the ticket used by K2 (visible at kernel boundary).
__global__ __launch_bounds__(BLOCK) void nll_part_kernel(
    const float* __restrict__ close_er,
    const int*   __restrict__ y,
    const float* __restrict__ max_dis,
    const float* __restrict__ margin_p,
    float*          __restrict__ p_sums,   // [R][512] f32
    unsigned short* __restrict__ p_cnts,   // [R][512] u16 (block count <= 1024)
    unsigned int*   __restrict__ g_ticket,
    int n)
{
    __shared__ float        s_md[N_CLASSES];
    __shared__ float        s_sum[N_CLASSES];
    __shared__ unsigned int s_cnt[N_CLASSES];

    const int tid = threadIdx.x;
    const float margin = margin_p[0];

    if (tid == 0 && blockIdx.x == 0) *g_ticket = 0u;  // reset for K2 (each call)

    if (tid < N_CLASSES) {
        s_md[tid]  = max_dis[tid];
        s_sum[tid] = 0.0f;
        s_cnt[tid] = 0u;
    }
    __syncthreads();

    const int i = blockIdx.x * BLOCK + tid;
    if (i < n) {
        const int c = y[i];
        // use-once line: nontemporal (no cache allocation)
        const float ce = __builtin_nontemporal_load(&close_er[(size_t)i * N_CLASSES + c]);
        const float x  = ce - s_md[c] - margin;
        float s = 1.0f / (1.0f + __expf(-x));
        s = fminf(fmaxf(s, EPS_F), 1.0f - EPS_F);
        atomicAdd(&s_sum[c], -__logf(s));
        atomicAdd(&s_cnt[c], 1u);
    }
    __syncthreads();

    if (tid < N_CLASSES) {
        const size_t o = (size_t)blockIdx.x * N_CLASSES + tid;
        p_sums[o] = s_sum[tid];                   // coalesced 2 KB
        p_cnts[o] = (unsigned short)s_cnt[tid];   // coalesced 1 KB
    }
}

// K2 fused: 16 blocks tree-reduce the partial matrix into q-rows; the
// last-finishing block (device-scope ticket) combines the q-rows, computes
// per-class means and the mean over non-empty classes, writes the scalar.
// Fences: one release fence per block (tid0's wave, after barrier has
// drained vmcnt) + one acquire fence in the last block — 16 wave-fences
// total, after all main-kernel HBM traffic is done.
__global__ __launch_bounds__(1024) void reduce_finalize_kernel(
    const float*          __restrict__ p_sums,
    const unsigned short* __restrict__ p_cnts,
    float* __restrict__ q_sums,   // [nb][512] f32
    float* __restrict__ q_cnts,   // [nb][512] f32 (exact: < 2^24)
    unsigned int* __restrict__ g_ticket,
    float* __restrict__ out,
    int R)
{
    __shared__ float s1[1024];
    __shared__ float c1[1024];
    __shared__ float s_red[32];
    __shared__ bool  s_last;

    const int t  = threadIdx.x;
    const int c  = t & (N_CLASSES - 1);
    const int g  = t >> 9;
    const int r0 = blockIdx.x * RB;

    // ---- stage 1: reduce this block's RB partial rows (coalesced) ----
    float        sum = 0.0f;
    unsigned int cnt = 0u;
    #pragma unroll
    for (int k = g; k < RB; k += 2) {
        const int r = r0 + k;
        if (r < R) {
            sum += p_sums[(size_t)r * N_CLASSES + c];
            cnt += p_cnts[(size_t)r * N_CLASSES + c];
        }
    }
    s1[t] = sum;
    c1[t] = (float)cnt;
    __syncthreads();

    if (t < N_CLASSES) {
        const size_t o = (size_t)blockIdx.x * N_CLASSES + t;
        q_sums[o] = s1[t] + s1[t + 512];
        q_cnts[o] = c1[t] + c1[t + 512];
    }
    __syncthreads();  // barrier drains vmcnt -> q stores at least in L2

    // ---- ticket: last block to arrive finalizes ----
    if (t == 0) {
        __threadfence();  // release: write back this XCD's dirty L2 lines
        const unsigned int old = atomicAdd(g_ticket, 1u);
        s_last = (old == gridDim.x - 1);
    }
    __syncthreads();
    if (!s_last) return;
    __threadfence();      // acquire: don't read stale q lines

    // ---- stage 2: combine nb q-rows (64 KB, L2/L3-resident) ----
    const int nb = gridDim.x;
    float S = 0.0f, C = 0.0f;
    for (int r = g; r < nb; r += 2) {
        S += q_sums[(size_t)r * N_CLASSES + c];
        C += q_cnts[(size_t)r * N_CLASSES + c];
    }
    s1[t] = S;
    c1[t] = C;
    __syncthreads();

    float m = 0.0f, j = 0.0f;
    if (t < N_CLASSES) {
        const float SS = s1[t] + s1[t + 512];
        const float CC = c1[t] + c1[t + 512];
        if (CC > 0.0f) { m = SS / CC; j = 1.0f; }
    }
    for (int off = 32; off > 0; off >>= 1) {
        m += __shfl_down(m, off);
        j += __shfl_down(j, off);
    }
    if ((t & 63) == 0) {
        s_red[(t >> 6) * 2]     = m;
        s_red[(t >> 6) * 2 + 1] = j;
    }
    __syncthreads();
    if (t == 0) {
        float M = 0.0f, J = 0.0f;
        for (int w = 0; w < 16; ++w) {
            M += s_red[w * 2];
            J += s_red[w * 2 + 1];
        }
        out[0] = M / J;
    }
}

// ---------------- Path B (fallback: R1's proven 3-node atomic path) --------

__global__ __launch_bounds__(BLOCK) void nll_hist_kernel(
    const float* __restrict__ close_er,
    const int*   __restrict__ y,
    const float* __restrict__ max_dis,
    const float* __restrict__ margin_p,
    float* __restrict__ g_sums,
    float* __restrict__ g_counts,
    int n)
{
    __shared__ float        s_md[N_CLASSES];
    __shared__ float        s_sum[N_CLASSES];
    __shared__ unsigned int s_cnt[N_CLASSES];

    const int tid = threadIdx.x;
    const float margin = margin_p[0];

    if (tid < N_CLASSES) {
        s_md[tid]  = max_dis[tid];
        s_sum[tid] = 0.0f;
        s_cnt[tid] = 0u;
    }
    __syncthreads();

    const int i = blockIdx.x * BLOCK + tid;
    if (i < n) {
        const int c = y[i];
        const float ce = __builtin_nontemporal_load(&close_er[(size_t)i * N_CLASSES + c]);
        const float x  = ce - s_md[c] - margin;
        float s = 1.0f / (1.0f + __expf(-x));
        s = fminf(fmaxf(s, EPS_F), 1.0f - EPS_F);
        atomicAdd(&s_sum[c], -__logf(s));
        atomicAdd(&s_cnt[c], 1u);
    }
    __syncthreads();

    if (tid < N_CLASSES) {
        const unsigned int cnt = s_cnt[tid];
        if (cnt != 0u) {
            atomicAdd(&g_sums[tid],   s_sum[tid]);
            atomicAdd(&g_counts[tid], (float)cnt);
        }
    }
}

__global__ __launch_bounds__(512) void finalize_kernel(
    const float* __restrict__ g_sums,
    const float* __restrict__ g_counts,
    float* __restrict__ out)
{
    __shared__ float s_red[16];
    const int t = threadIdx.x;
    float m = 0.0f, j = 0.0f;
    const float cnt = g_counts[t];
    if (cnt > 0.0f) { m = g_sums[t] / cnt; j = 1.0f; }
    for (int off = 32; off > 0; off >>= 1) {
        m += __shfl_down(m, off);
        j += __shfl_down(j, off);
    }
    if ((t & 63) == 0) {
        s_red[(t >> 6) * 2]     = m;
        s_red[(t >> 6) * 2 + 1] = j;
    }
    __syncthreads();
    if (t == 0) {
        float M = 0.0f, J = 0.0f;
        for (int w = 0; w < 8; ++w) {
            M += s_red[w * 2];
            J += s_red[w * 2 + 1];
        }
        out[0] = M / J;
    }
}

// ---------------------------------------------------------------------------

extern "C" void kernel_launch(void* const* d_in, const int* in_sizes, int n_in,
                              void* d_out, int out_size, void* d_ws, size_t ws_size,
                              hipStream_t stream) {
    const float* close_er = (const float*)d_in[0];
    const int*   y        = (const int*)d_in[1];
    const float* max_dis  = (const float*)d_in[2];
    const float* margin   = (const float*)d_in[3];
    float* out = (float*)d_out;

    const int n  = in_sizes[1];               // N samples
    const int R  = (n + BLOCK - 1) / BLOCK;   // 256 partial rows
    const int nb = (R + RB - 1) / RB;         // 16 reduce blocks

    const size_t p_bytes = (size_t)R * N_CLASSES * 6;                    // f32 + u16
    const size_t q_bytes = (size_t)nb * N_CLASSES * 2 * sizeof(float);
    const size_t need    = p_bytes + q_bytes + sizeof(unsigned int);

    if (ws_size >= need) {
        // Path A: 2 nodes, no atomics in main flush, no memset.
        float*          p_sums   = (float*)d_ws;
        unsigned short* p_cnts   = (unsigned short*)(p_sums + (size_t)R * N_CLASSES);
        float*          q_sums   = (float*)((char*)d_ws + p_bytes);
        float*          q_cnts   = q_sums + (size_t)nb * N_CLASSES;
        unsigned int*   g_ticket = (unsigned int*)(q_cnts + (size_t)nb * N_CLASSES);

        nll_part_kernel<<<R, BLOCK, 0, stream>>>(close_er, y, max_dis, margin,
                                                 p_sums, p_cnts, g_ticket, n);
        reduce_finalize_kernel<<<nb, 1024, 0, stream>>>(p_sums, p_cnts,
                                                        q_sums, q_cnts,
                                                        g_ticket, out, R);
    } else {
        // Path B: proven 3-node atomic path (R1).
        float* g_sums   = (float*)d_ws;
        float* g_counts = g_sums + N_CLASSES;
        hipMemsetAsync(d_ws, 0, 2 * N_CLASSES * sizeof(float), stream);
        nll_hist_kernel<<<R, BLOCK, 0, stream>>>(close_er, y, max_dis, margin,
                                                 g_sums, g_counts, n);
        finalize_kernel<<<1, N_CLASSES, 0, stream>>>(g_sums, g_counts, out);
    }
}

// Round 7
// 20.762 us; speedup vs baseline: 1.0853x; 1.0853x over previous
//
#include <hip/hip_runtime.h>

#define N_CLASSES 512
#define EPS_F 1e-7f

// ---------------- Path A (atomic-free, 3 nodes, no memset) ----------------
// K1 templated on block size: gather + NLL + per-block LDS class histogram;
// flush = coalesced plain stores of per-block partials (every slot written
// unconditionally -> no zero-init of ws needed).
template <int BLK>
__global__ __launch_bounds__(BLK) void nll_part_kernel(
    const float* __restrict__ close_er,
    const int*   __restrict__ y,
    const float* __restrict__ max_dis,
    const float* __restrict__ margin_p,
    float*          __restrict__ p_sums,   // [R][512] f32
    unsigned short* __restrict__ p_cnts,   // [R][512] u16 (block count <= BLK)
    int n)
{
    __shared__ float        s_md[N_CLASSES];
    __shared__ float        s_sum[N_CLASSES];
    __shared__ unsigned int s_cnt[N_CLASSES];

    const int tid = threadIdx.x;
    const float margin = margin_p[0];

    for (int c = tid; c < N_CLASSES; c += BLK) {
        s_md[c]  = max_dis[c];
        s_sum[c] = 0.0f;
        s_cnt[c] = 0u;
    }
    __syncthreads();

    const int i = blockIdx.x * BLK + tid;
    if (i < n) {
        const int c = y[i];
        // use-once line: nontemporal (no cache allocation)
        const float ce = __builtin_nontemporal_load(&close_er[(size_t)i * N_CLASSES + c]);
        const float x  = ce - s_md[c] - margin;
        float s = 1.0f / (1.0f + __expf(-x));
        s = fminf(fmaxf(s, EPS_F), 1.0f - EPS_F);
        atomicAdd(&s_sum[c], -__logf(s));
        atomicAdd(&s_cnt[c], 1u);
    }
    __syncthreads();

    for (int c = tid; c < N_CLASSES; c += BLK) {
        const size_t o = (size_t)blockIdx.x * N_CLASSES + c;
        p_sums[o] = s_sum[c];                   // coalesced 2 KB
        p_cnts[o] = (unsigned short)s_cnt[c];   // coalesced 1 KB
    }
}

// K2a: tree stage. Block b reduces partial rows [b*rb, b*rb+rb);
// thread t owns class t&511, row-phase t>>9 -> fully coalesced.
__global__ __launch_bounds__(1024) void reduce_part_kernel(
    const float*          __restrict__ p_sums,
    const unsigned short* __restrict__ p_cnts,
    float* __restrict__ q_sums,   // [nb][512] f32
    float* __restrict__ q_cnts,   // [nb][512] f32 (exact: < 2^24)
    int R, int rb)
{
    __shared__ float s1[1024];
    __shared__ float c1[1024];

    const int t = threadIdx.x;
    const int c = t & (N_CLASSES - 1);
    const int g = t >> 9;
    const int r0 = blockIdx.x * rb;

    float        sum = 0.0f;
    unsigned int cnt = 0u;
    for (int k = g; k < rb; k += 2) {
        const int r = r0 + k;
        if (r < R) {
            sum += p_sums[(size_t)r * N_CLASSES + c];
            cnt += p_cnts[(size_t)r * N_CLASSES + c];
        }
    }
    s1[t] = sum;
    c1[t] = (float)cnt;
    __syncthreads();

    if (t < N_CLASSES) {
        const size_t o = (size_t)blockIdx.x * N_CLASSES + t;
        q_sums[o] = s1[t] + s1[t + 512];
        q_cnts[o] = c1[t] + c1[t + 512];
    }
}

// K3: one block combines nb q-rows, per-class mean, mean over non-empty
// classes -> scalar.
__global__ __launch_bounds__(1024) void finalize_part_kernel(
    const float* __restrict__ q_sums,
    const float* __restrict__ q_cnts,
    float* __restrict__ out,
    int nb)
{
    __shared__ float s1[1024];
    __shared__ float c1[1024];
    __shared__ float s_red[32];

    const int t = threadIdx.x;
    const int c = t & (N_CLASSES - 1);
    const int g = t >> 9;

    float sum = 0.0f, cnt = 0.0f;
    for (int r = g; r < nb; r += 2) {
        sum += q_sums[(size_t)r * N_CLASSES + c];
        cnt += q_cnts[(size_t)r * N_CLASSES + c];
    }
    s1[t] = sum;
    c1[t] = cnt;
    __syncthreads();

    float m = 0.0f, j = 0.0f;
    if (t < N_CLASSES) {
        const float S = s1[t] + s1[t + 512];
        const float C = c1[t] + c1[t + 512];
        if (C > 0.0f) { m = S / C; j = 1.0f; }
    }
    for (int off = 32; off > 0; off >>= 1) {
        m += __shfl_down(m, off);
        j += __shfl_down(j, off);
    }
    if ((t & 63) == 0) {
        s_red[(t >> 6) * 2]     = m;
        s_red[(t >> 6) * 2 + 1] = j;
    }
    __syncthreads();
    if (t == 0) {
        float M = 0.0f, J = 0.0f;
        for (int w = 0; w < 16; ++w) {
            M += s_red[w * 2];
            J += s_red[w * 2 + 1];
        }
        out[0] = M / J;
    }
}

// ---------------- Path B (fallback: R1's proven 3-node atomic path) --------

__global__ __launch_bounds__(1024) void nll_hist_kernel(
    const float* __restrict__ close_er,
    const int*   __restrict__ y,
    const float* __restrict__ max_dis,
    const float* __restrict__ margin_p,
    float* __restrict__ g_sums,
    float* __restrict__ g_counts,
    int n)
{
    __shared__ float        s_md[N_CLASSES];
    __shared__ float        s_sum[N_CLASSES];
    __shared__ unsigned int s_cnt[N_CLASSES];

    const int tid = threadIdx.x;
    const float margin = margin_p[0];

    if (tid < N_CLASSES) {
        s_md[tid]  = max_dis[tid];
        s_sum[tid] = 0.0f;
        s_cnt[tid] = 0u;
    }
    __syncthreads();

    const int i = blockIdx.x * 1024 + tid;
    if (i < n) {
        const int c = y[i];
        const float ce = __builtin_nontemporal_load(&close_er[(size_t)i * N_CLASSES + c]);
        const float x  = ce - s_md[c] - margin;
        float s = 1.0f / (1.0f + __expf(-x));
        s = fminf(fmaxf(s, EPS_F), 1.0f - EPS_F);
        atomicAdd(&s_sum[c], -__logf(s));
        atomicAdd(&s_cnt[c], 1u);
    }
    __syncthreads();

    if (tid < N_CLASSES) {
        const unsigned int cnt = s_cnt[tid];
        if (cnt != 0u) {
            atomicAdd(&g_sums[tid],   s_sum[tid]);
            atomicAdd(&g_counts[tid], (float)cnt);
        }
    }
}

__global__ __launch_bounds__(512) void finalize_kernel(
    const float* __restrict__ g_sums,
    const float* __restrict__ g_counts,
    float* __restrict__ out)
{
    __shared__ float s_red[16];
    const int t = threadIdx.x;
    float m = 0.0f, j = 0.0f;
    const float cnt = g_counts[t];
    if (cnt > 0.0f) { m = g_sums[t] / cnt; j = 1.0f; }
    for (int off = 32; off > 0; off >>= 1) {
        m += __shfl_down(m, off);
        j += __shfl_down(j, off);
    }
    if ((t & 63) == 0) {
        s_red[(t >> 6) * 2]     = m;
        s_red[(t >> 6) * 2 + 1] = j;
    }
    __syncthreads();
    if (t == 0) {
        float M = 0.0f, J = 0.0f;
        for (int w = 0; w < 8; ++w) {
            M += s_red[w * 2];
            J += s_red[w * 2 + 1];
        }
        out[0] = M / J;
    }
}

// ---------------------------------------------------------------------------

static inline void launch_pathA(const float* close_er, const int* y,
                                const float* max_dis, const float* margin,
                                float* out, void* d_ws, int n, int blk,
                                hipStream_t stream) {
    const int R  = (n + blk - 1) / blk;
    const int nb = 16;
    const int rb = (R + nb - 1) / nb;

    float*          p_sums = (float*)d_ws;
    unsigned short* p_cnts = (unsigned short*)(p_sums + (size_t)R * N_CLASSES);
    float*          q_sums = (float*)((char*)d_ws + (size_t)R * N_CLASSES * 6);
    float*          q_cnts = q_sums + (size_t)nb * N_CLASSES;

    if (blk == 512) {
        nll_part_kernel<512><<<R, 512, 0, stream>>>(close_er, y, max_dis, margin,
                                                    p_sums, p_cnts, n);
    } else {
        nll_part_kernel<1024><<<R, 1024, 0, stream>>>(close_er, y, max_dis, margin,
                                                      p_sums, p_cnts, n);
    }
    reduce_part_kernel<<<nb, 1024, 0, stream>>>(p_sums, p_cnts, q_sums, q_cnts, R, rb);
    finalize_part_kernel<<<1, 1024, 0, stream>>>(q_sums, q_cnts, out, nb);
}

extern "C" void kernel_launch(void* const* d_in, const int* in_sizes, int n_in,
                              void* d_out, int out_size, void* d_ws, size_t ws_size,
                              hipStream_t stream) {
    const float* close_er = (const float*)d_in[0];
    const int*   y        = (const int*)d_in[1];
    const float* max_dis  = (const float*)d_in[2];
    const float* margin   = (const float*)d_in[3];
    float* out = (float*)d_out;

    const int n = in_sizes[1];  // N samples

    auto needA = [&](int blk) -> size_t {
        const int R = (n + blk - 1) / blk;
        return (size_t)R * N_CLASSES * 6 + (size_t)16 * N_CLASSES * 2 * sizeof(float);
    };

    if (ws_size >= needA(512)) {
        // Path A, 512-thread K1 blocks -> 2 blocks/CU (tail overlap).
        launch_pathA(close_er, y, max_dis, margin, out, d_ws, n, 512, stream);
    } else if (ws_size >= needA(1024)) {
        // Path A, R5-exact (1024-thread K1 blocks).
        launch_pathA(close_er, y, max_dis, margin, out, d_ws, n, 1024, stream);
    } else {
        // Path B: proven 3-node atomic path (R1).
        const int R = (n + 1023) / 1024;
        float* g_sums   = (float*)d_ws;
        float* g_counts = g_sums + N_CLASSES;
        hipMemsetAsync(d_ws, 0, 2 * N_CLASSES * sizeof(float), stream);
        nll_hist_kernel<<<R, 1024, 0, stream>>>(close_er, y, max_dis, margin,
                                                g_sums, g_counts, n);
        finalize_kernel<<<1, N_CLASSES, 0, stream>>>(g_sums, g_counts, out);
    }
}

// Round 8
// 19.286 us; speedup vs baseline: 1.1683x; 1.0765x over previous
//
#include <hip/hip_runtime.h>

#define N_CLASSES 512
#define EPS_F 1e-7f
#define BLOCK 1024
#define RB 16  // rows per K2a block

// ---------------- Path A (atomic-free, 3 nodes, no memset) ----------------
// R5 champion, bit-exact revert.

// K1: gather + NLL + per-block LDS class histogram; flush = coalesced plain
// stores of per-block partials (every slot written -> no zero-init needed).
__global__ __launch_bounds__(BLOCK) void nll_part_kernel(
    const float* __restrict__ close_er,
    const int*   __restrict__ y,
    const float* __restrict__ max_dis,
    const float* __restrict__ margin_p,
    float*          __restrict__ p_sums,   // [R][512] f32
    unsigned short* __restrict__ p_cnts,   // [R][512] u16 (block count <= 1024)
    int n)
{
    __shared__ float        s_md[N_CLASSES];
    __shared__ float        s_sum[N_CLASSES];
    __shared__ unsigned int s_cnt[N_CLASSES];

    const int tid = threadIdx.x;
    const float margin = margin_p[0];

    if (tid < N_CLASSES) {
        s_md[tid]  = max_dis[tid];
        s_sum[tid] = 0.0f;
        s_cnt[tid] = 0u;
    }
    __syncthreads();

    const int i = blockIdx.x * BLOCK + tid;
    if (i < n) {
        const int c = y[i];
        // use-once line: nontemporal (no cache allocation)
        const float ce = __builtin_nontemporal_load(&close_er[(size_t)i * N_CLASSES + c]);
        const float x  = ce - s_md[c] - margin;
        float s = 1.0f / (1.0f + __expf(-x));
        s = fminf(fmaxf(s, EPS_F), 1.0f - EPS_F);
        atomicAdd(&s_sum[c], -__logf(s));
        atomicAdd(&s_cnt[c], 1u);
    }
    __syncthreads();

    if (tid < N_CLASSES) {
        const size_t o = (size_t)blockIdx.x * N_CLASSES + tid;
        p_sums[o] = s_sum[tid];                   // coalesced 2 KB
        p_cnts[o] = (unsigned short)s_cnt[tid];   // coalesced 1 KB
    }
}

// K2a: tree stage. Block b reduces rows [b*RB, b*RB+RB) of the partial
// matrix; thread t owns class t&511, row-phase t>>9 -> fully coalesced.
__global__ __launch_bounds__(1024) void reduce_part_kernel(
    const float*          __restrict__ p_sums,
    const unsigned short* __restrict__ p_cnts,
    float* __restrict__ q_sums,   // [nb][512] f32
    float* __restrict__ q_cnts,   // [nb][512] f32 (exact: < 2^24)
    int R)
{
    __shared__ float s1[1024];
    __shared__ float c1[1024];

    const int t = threadIdx.x;
    const int c = t & (N_CLASSES - 1);
    const int g = t >> 9;
    const int r0 = blockIdx.x * RB;

    float        sum = 0.0f;
    unsigned int cnt = 0u;
    #pragma unroll
    for (int k = g; k < RB; k += 2) {
        const int r = r0 + k;
        if (r < R) {
            sum += p_sums[(size_t)r * N_CLASSES + c];
            cnt += p_cnts[(size_t)r * N_CLASSES + c];
        }
    }
    s1[t] = sum;
    c1[t] = (float)cnt;
    __syncthreads();

    if (t < N_CLASSES) {
        const size_t o = (size_t)blockIdx.x * N_CLASSES + t;
        q_sums[o] = s1[t] + s1[t + 512];
        q_cnts[o] = c1[t] + c1[t + 512];
    }
}

// K3: final. One block combines nb q-rows, per-class mean, mean over
// non-empty classes -> scalar.
__global__ __launch_bounds__(1024) void finalize_part_kernel(
    const float* __restrict__ q_sums,
    const float* __restrict__ q_cnts,
    float* __restrict__ out,
    int nb)
{
    __shared__ float s1[1024];
    __shared__ float c1[1024];
    __shared__ float s_red[32];

    const int t = threadIdx.x;
    const int c = t & (N_CLASSES - 1);
    const int g = t >> 9;

    float sum = 0.0f, cnt = 0.0f;
    for (int r = g; r < nb; r += 2) {
        sum += q_sums[(size_t)r * N_CLASSES + c];
        cnt += q_cnts[(size_t)r * N_CLASSES + c];
    }
    s1[t] = sum;
    c1[t] = cnt;
    __syncthreads();

    float m = 0.0f, j = 0.0f;
    if (t < N_CLASSES) {
        const float S = s1[t] + s1[t + 512];
        const float C = c1[t] + c1[t + 512];
        if (C > 0.0f) { m = S / C; j = 1.0f; }
    }
    for (int off = 32; off > 0; off >>= 1) {
        m += __shfl_down(m, off);
        j += __shfl_down(j, off);
    }
    if ((t & 63) == 0) {
        s_red[(t >> 6) * 2]     = m;
        s_red[(t >> 6) * 2 + 1] = j;
    }
    __syncthreads();
    if (t == 0) {
        float M = 0.0f, J = 0.0f;
        for (int w = 0; w < 16; ++w) {
            M += s_red[w * 2];
            J += s_red[w * 2 + 1];
        }
        out[0] = M / J;
    }
}

// ---------------- Path B (fallback: R1's proven 3-node atomic path) --------

__global__ __launch_bounds__(BLOCK) void nll_hist_kernel(
    const float* __restrict__ close_er,
    const int*   __restrict__ y,
    const float* __restrict__ max_dis,
    const float* __restrict__ margin_p,
    float* __restrict__ g_sums,
    float* __restrict__ g_counts,
    int n)
{
    __shared__ float        s_md[N_CLASSES];
    __shared__ float        s_sum[N_CLASSES];
    __shared__ unsigned int s_cnt[N_CLASSES];

    const int tid = threadIdx.x;
    const float margin = margin_p[0];

    if (tid < N_CLASSES) {
        s_md[tid]  = max_dis[tid];
        s_sum[tid] = 0.0f;
        s_cnt[tid] = 0u;
    }
    __syncthreads();

    const int i = blockIdx.x * BLOCK + tid;
    if (i < n) {
        const int c = y[i];
        const float ce = __builtin_nontemporal_load(&close_er[(size_t)i * N_CLASSES + c]);
        const float x  = ce - s_md[c] - margin;
        float s = 1.0f / (1.0f + __expf(-x));
        s = fminf(fmaxf(s, EPS_F), 1.0f - EPS_F);
        atomicAdd(&s_sum[c], -__logf(s));
        atomicAdd(&s_cnt[c], 1u);
    }
    __syncthreads();

    if (tid < N_CLASSES) {
        const unsigned int cnt = s_cnt[tid];
        if (cnt != 0u) {
            atomicAdd(&g_sums[tid],   s_sum[tid]);
            atomicAdd(&g_counts[tid], (float)cnt);
        }
    }
}

__global__ __launch_bounds__(512) void finalize_kernel(
    const float* __restrict__ g_sums,
    const float* __restrict__ g_counts,
    float* __restrict__ out)
{
    __shared__ float s_red[16];
    const int t = threadIdx.x;
    float m = 0.0f, j = 0.0f;
    const float cnt = g_counts[t];
    if (cnt > 0.0f) { m = g_sums[t] / cnt; j = 1.0f; }
    for (int off = 32; off > 0; off >>= 1) {
        m += __shfl_down(m, off);
        j += __shfl_down(j, off);
    }
    if ((t & 63) == 0) {
        s_red[(t >> 6) * 2]     = m;
        s_red[(t >> 6) * 2 + 1] = j;
    }
    __syncthreads();
    if (t == 0) {
        float M = 0.0f, J = 0.0f;
        for (int w = 0; w < 8; ++w) {
            M += s_red[w * 2];
            J += s_red[w * 2 + 1];
        }
        out[0] = M / J;
    }
}

// ---------------------------------------------------------------------------

extern "C" void kernel_launch(void* const* d_in, const int* in_sizes, int n_in,
                              void* d_out, int out_size, void* d_ws, size_t ws_size,
                              hipStream_t stream) {
    const float* close_er = (const float*)d_in[0];
    const int*   y        = (const int*)d_in[1];
    const float* max_dis  = (const float*)d_in[2];
    const float* margin   = (const float*)d_in[3];
    float* out = (float*)d_out;

    const int n    = in_sizes[1];               // N samples
    const int R    = (n + BLOCK - 1) / BLOCK;   // 256 partial rows
    const int nb   = (R + RB - 1) / RB;         // 16 tree blocks

    const size_t pA_bytes = (size_t)R * N_CLASSES * (sizeof(float) + sizeof(unsigned short));
    const size_t qA_bytes = (size_t)nb * N_CLASSES * 2 * sizeof(float);

    if (ws_size >= pA_bytes + qA_bytes) {
        // Path A: 3 nodes, no atomics, no memset.
        float*          p_sums = (float*)d_ws;
        unsigned short* p_cnts = (unsigned short*)(p_sums + (size_t)R * N_CLASSES);
        float*          q_sums = (float*)((char*)d_ws + (size_t)R * N_CLASSES * 6);
        float*          q_cnts = q_sums + (size_t)nb * N_CLASSES;

        nll_part_kernel<<<R, BLOCK, 0, stream>>>(close_er, y, max_dis, margin,
                                                 p_sums, p_cnts, n);
        reduce_part_kernel<<<nb, 1024, 0, stream>>>(p_sums, p_cnts, q_sums, q_cnts, R);
        finalize_part_kernel<<<1, 1024, 0, stream>>>(q_sums, q_cnts, out, nb);
    } else {
        // Path B: proven 3-node atomic path (R1).
        float* g_sums   = (float*)d_ws;
        float* g_counts = g_sums + N_CLASSES;
        hipMemsetAsync(d_ws, 0, 2 * N_CLASSES * sizeof(float), stream);
        nll_hist_kernel<<<R, BLOCK, 0, stream>>>(close_er, y, max_dis, margin,
                                                 g_sums, g_counts, n);
        finalize_kernel<<<1, N_CLASSES, 0, stream>>>(g_sums, g_counts, out);
    }
}